// Round 1
// baseline (350.236 us; speedup 1.0000x reference)
//
#include <hip/hip_runtime.h>
#include <hip/hip_bf16.h>

// ---------------------------------------------------------------------------
// RPN_Modulator fused pipeline (3 kernels):
//   k_q   : qpart[s,k,bi,c] = partial_c' modulator[bi,c'] * pm_w[k,c,c']   (4-way K-split)
//   k_w2  : w2[k,bi,o,c] = bf16(po_w[k,o,c] * (sum_s qpart + pm_b[k,c]))   (row-major)
//   k_gemm: out[k,bi,o,n] = sum_c w2[o,c]*bf16(feats[k][b,c,n]) + po_b[k,o]
//
// Round-0 changes vs 218us baseline:
//  * k_gemm: SWAPPED MFMA operands (A=feats from LDS, B=w2 from L2). D-frag
//    now has row=n, col=o -> each lane's 4 acc values are 4 consecutive n
//    -> one nontemporal dwordx4 store per fragment (was 4 scalar dwords).
//    128->32 store instrs per lane per block; vmcnt drain between instances
//    4x cheaper. Same LDS swizzle, same global burst patterns, same VGPR.
//  * k_q: 4 outputs per block (grid.x 64), halves modulator L2 re-reads.
// ---------------------------------------------------------------------------

typedef __bf16 bf16x8 __attribute__((ext_vector_type(8)));
typedef float  f32x4  __attribute__((ext_vector_type(4)));
typedef unsigned short u16;

__device__ __forceinline__ unsigned pack2(float lo, float hi) {
    __hip_bfloat162 h = __float22bfloat162_rn(make_float2(lo, hi));
    union { __hip_bfloat162 h; unsigned u; } cv; cv.h = h; return cv.u;
}

// tiles-of-64 per level: {400,100,25,7,2}, total 534
__device__ __forceinline__ void decode_tile(int x, int& k, int& nt, int& N, size_t& oo) {
    if (x < 400)      { k = 0; nt = x;       N = 25600; oo = 0; }
    else if (x < 500) { k = 1; nt = x - 400; N = 6400;  oo = 104857600; }
    else if (x < 525) { k = 2; nt = x - 500; N = 1600;  oo = 131072000; }
    else if (x < 532) { k = 3; nt = x - 525; N = 400;   oo = 137625600; }
    else              { k = 4; nt = x - 532; N = 100;   oo = 139264000; }
}

// ---------------- Kernel 1: q partials, 4-way split over K ----------------
// 4 outputs per block: halves modulator L2 traffic vs 2-output version.
__global__ __launch_bounds__(256) void k_q(
    const float* __restrict__ modulator,  // [16][12544]
    const float* __restrict__ pm_w,       // [5][256][12544]
    float* __restrict__ qpart)            // [4][5][16][256]
{
    int o4 = blockIdx.x;                  // outputs o4 + {0,64,128,192}
    int k  = blockIdx.y;
    int s  = blockIdx.z;                  // K-split 0..3, 784 float4 each
    int t  = threadIdx.x;
    float acc[4][16];
#pragma unroll
    for (int j = 0; j < 4; ++j)
#pragma unroll
        for (int bi = 0; bi < 16; ++bi) acc[j][bi] = 0.f;
    const float4* mod4 = (const float4*)modulator;
    const float4* wp0 = (const float4*)(pm_w + ((size_t)k * 256 + o4      ) * 12544);
    const float4* wp1 = (const float4*)(pm_w + ((size_t)k * 256 + o4 +  64) * 12544);
    const float4* wp2 = (const float4*)(pm_w + ((size_t)k * 256 + o4 + 128) * 12544);
    const float4* wp3 = (const float4*)(pm_w + ((size_t)k * 256 + o4 + 192) * 12544);
    for (int it = 0; it < 4; ++it) {
        int jj = it * 256 + t;
        if (jj < 784) {
            int jx = s * 784 + jj;
            float4 wv0 = wp0[jx], wv1 = wp1[jx], wv2 = wp2[jx], wv3 = wp3[jx];
#pragma unroll
            for (int bi = 0; bi < 16; ++bi) {
                float4 m = mod4[bi * 3136 + jx];
                acc[0][bi] += wv0.x * m.x + wv0.y * m.y + wv0.z * m.z + wv0.w * m.w;
                acc[1][bi] += wv1.x * m.x + wv1.y * m.y + wv1.z * m.z + wv1.w * m.w;
                acc[2][bi] += wv2.x * m.x + wv2.y * m.y + wv2.z * m.z + wv2.w * m.w;
                acc[3][bi] += wv3.x * m.x + wv3.y * m.y + wv3.z * m.z + wv3.w * m.w;
            }
        }
    }
#pragma unroll
    for (int j = 0; j < 4; ++j)
#pragma unroll
        for (int bi = 0; bi < 16; ++bi)
#pragma unroll
            for (int off = 32; off > 0; off >>= 1)
                acc[j][bi] += __shfl_down(acc[j][bi], off);
    __shared__ float red[4][64];
    int w = t >> 6, lane = t & 63;
    if (lane == 0) {
#pragma unroll
        for (int j = 0; j < 4; ++j)
#pragma unroll
            for (int bi = 0; bi < 16; ++bi) red[w][j * 16 + bi] = acc[j][bi];
    }
    __syncthreads();
    if (t < 64) {
        float v = red[0][t] + red[1][t] + red[2][t] + red[3][t];
        int bi = t & 15;
        int o  = o4 + (t >> 4) * 64;
        qpart[(((size_t)s * 5 + k) * 16 + bi) * 256 + o] = v;
    }
}

// ---------------- Kernel 2: W2 = bf16(po_w * (sum qpart + pm_b)), 4c/thread
__global__ __launch_bounds__(256) void k_w2(
    const float* __restrict__ po_w,       // [5][256][256]
    const float* __restrict__ pm_b,       // [5][256]
    const float* __restrict__ qpart,      // [4][5][16][256]
    u16* __restrict__ w2)                 // [5][16][256][256] bf16
{
    int idx4 = blockIdx.x * 256 + threadIdx.x;   // 5*2^18 threads, 4 c each
    int c4 = idx4 & 63;
    int o  = (idx4 >> 6) & 255;
    int bi = (idx4 >> 14) & 15;
    int k  = idx4 >> 18;
    size_t qi = ((size_t)(k * 16 + bi)) * 256 + c4 * 4;
    f32x4 q0 = *(const f32x4*)(qpart + qi);
    f32x4 q1 = *(const f32x4*)(qpart + qi + 20480);
    f32x4 q2 = *(const f32x4*)(qpart + qi + 40960);
    f32x4 q3 = *(const f32x4*)(qpart + qi + 61440);
    f32x4 pb = *(const f32x4*)(pm_b + k * 256 + c4 * 4);
    f32x4 q  = q0 + q1 + q2 + q3 + pb;
    f32x4 w  = *(const f32x4*)(po_w + ((size_t)(k * 256 + o)) * 256 + c4 * 4);
    uint2 r;
    r.x = pack2(w[0] * q[0], w[1] * q[1]);
    r.y = pack2(w[2] * q[2], w[3] * q[3]);
    *(uint2*)(w2 + (size_t)idx4 * 4) = r;
}

// ---------------- Kernel 3: fused transpose + GEMM over all levels ---------
// block: 512 threads = 8 waves; 64 out-cols x full M=256 x 4 instances.
// SWAPPED operands: A = feats tile (LDS, [n][c] swizzled), B = w2 (global).
// Wave (wo = w&3, wn = w>>2) owns o in [wo*64, wo*64+64), n in [wn*32, wn*32+32).
// acc[2][4]: D row = n (lg*4+reg), col = o (lr) -> dwordx4 stores along n.
__global__ __launch_bounds__(512, 4) void k_gemm(
    const float* __restrict__ f0, const float* __restrict__ f1,
    const float* __restrict__ f2, const float* __restrict__ f3,
    const float* __restrict__ f4,
    const u16* __restrict__ w2,      // [k][bi][o][c] bf16 row-major
    const float* __restrict__ po_b,  // [5][256]
    float* __restrict__ out)         // [k][bi][o][n] fp32
{
    __shared__ __align__(16) u16 ldsB[64 * 256];
    int k, nt, N; size_t oo;
    decode_tile(blockIdx.x, k, nt, N, oo);
    const float* fsrc = (k == 0) ? f0 : (k == 1) ? f1 : (k == 2) ? f2 : (k == 3) ? f3 : f4;
    const int b = blockIdx.y;
    const int t = threadIdx.x;
    const int n0 = nt * 64;

    // ---- stage: fp32 [c][n] -> bf16 LDS [n][c], swizzled; single sync ----
    {
        const float* s = fsrc + (size_t)b * 256 * N + n0;
        int ng = t & 15, grp = t >> 4;          // ng: float4 along n; grp 0..31: c-pair group
        bool inb = (n0 + ng * 4) < N;           // N%4==0 -> whole float4 in/out
#pragma unroll
        for (int j = 0; j < 4; ++j) {
            int p = j * 32 + grp;               // c-pair 0..127 (c=2p,2p+1)
            f32x4 v0 = {0.f, 0.f, 0.f, 0.f}, v1 = {0.f, 0.f, 0.f, 0.f};
            if (inb) {
                v0 = *(const f32x4*)(s + (size_t)(2 * p) * N + ng * 4);
                v1 = *(const f32x4*)(s + (size_t)(2 * p + 1) * N + ng * 4);
            }
#pragma unroll
            for (int e = 0; e < 4; ++e) {
                int n = ng * 4 + e;
                unsigned off = (unsigned)(n << 9) + (unsigned)(p << 2);
                off ^= (unsigned)((n & 7) << 4);
                *(unsigned*)((char*)ldsB + off) = pack2(v0[e], v1[e]);
            }
        }
    }
    __syncthreads();

    const int lane = t & 63, w = t >> 6;
    const int lr = lane & 15, lg = lane >> 4;
    const int wo = w & 3, wn = w >> 2;          // o-chunk 0..3, n-half 0..1
    const float* pb = po_b + k * 256;
    float* obase0 = out + oo;

    // LDS A-read bases: row n = wn*32 + mi*16 + lr, byte = (row<<9)+(kk<<6)+(lg<<4)
    // XOR (row&7)<<4. Fields of base (bits 4-6) and kk (bits 6-8) overlap only
    // at bit 6, so folding kk via XOR reproduces the staged swizzle exactly.
    unsigned abase[2];
#pragma unroll
    for (int mi = 0; mi < 2; ++mi) {
        int row = wn * 32 + mi * 16 + lr;
        unsigned off = (unsigned)(row << 9) + (unsigned)(lg << 4);
        off ^= (unsigned)((row & 7) << 4);
        abase[mi] = off;
    }

    float bias[4];
#pragma unroll
    for (int ni = 0; ni < 4; ++ni) bias[ni] = pb[wo * 64 + ni * 16 + lr];

#pragma unroll 1
    for (int i = 0; i < 4; ++i) {
        const u16* wsrc = w2 + ((size_t)(k * 16 + b * 4 + i) << 16)
                        + (size_t)(wo * 64 + lr) * 256 + lg * 8;
        float* obase = obase0 + (size_t)(b * 4 + i) * 256 * N;
        f32x4 acc[2][4];
#pragma unroll
        for (int mi = 0; mi < 2; ++mi)
#pragma unroll
            for (int ni = 0; ni < 4; ++ni)
                acc[mi][ni] = (f32x4){0.f, 0.f, 0.f, 0.f};

#pragma unroll 4
        for (int kk = 0; kk < 8; ++kk) {        // K = 256 = 8 x 32
            bf16x8 a[2], bw[4];
#pragma unroll
            for (int mi = 0; mi < 2; ++mi)
                a[mi] = *(const bf16x8*)((const char*)ldsB + (abase[mi] ^ (unsigned)(kk << 6)));
#pragma unroll
            for (int ni = 0; ni < 4; ++ni)
                bw[ni] = *(const bf16x8*)(wsrc + ni * 4096 + kk * 32);
#pragma unroll
            for (int mi = 0; mi < 2; ++mi)
#pragma unroll
                for (int ni = 0; ni < 4; ++ni)
                    acc[mi][ni] = __builtin_amdgcn_mfma_f32_16x16x32_bf16(a[mi], bw[ni], acc[mi][ni], 0, 0, 0);
        }

        // epilogue: lane holds out[o=wo*64+ni*16+lr][n = n0+wn*32+mi*16+lg*4 .. +3]
#pragma unroll
        for (int mi = 0; mi < 2; ++mi) {
            int nbase = n0 + wn * 32 + mi * 16 + lg * 4;
            if (nbase < N) {                    // N%4==0 -> whole float4 in/out
#pragma unroll
                for (int ni = 0; ni < 4; ++ni) {
                    int orow = wo * 64 + ni * 16 + lr;
                    f32x4 v = acc[mi][ni];
                    v[0] += bias[ni]; v[1] += bias[ni]; v[2] += bias[ni]; v[3] += bias[ni];
                    __builtin_nontemporal_store(v, (f32x4*)(obase + (size_t)orow * N + nbase));
                }
            }
        }
    }
}

// ---------------------------------------------------------------------------
extern "C" void kernel_launch(void* const* d_in, const int* in_sizes, int n_in,
                              void* d_out, int out_size, void* d_ws, size_t ws_size,
                              hipStream_t stream) {
    const float* f0 = (const float*)d_in[0];
    const float* f1 = (const float*)d_in[1];
    const float* f2 = (const float*)d_in[2];
    const float* f3 = (const float*)d_in[3];
    const float* f4 = (const float*)d_in[4];
    const float* modulator = (const float*)d_in[5];
    const float* pm_w = (const float*)d_in[6];
    const float* pm_b = (const float*)d_in[7];
    const float* po_w = (const float*)d_in[8];
    const float* po_b = (const float*)d_in[9];
    float* out = (float*)d_out;

    // workspace: w2 bf16 (5,242,880 u16) | qpart (81,920 f32)  ~= 10.8 MB
    u16* w2 = (u16*)d_ws;
    float* qpart = (float*)(w2 + (size_t)5 * 16 * 256 * 256);

    k_q<<<dim3(64, 5, 4), 256, 0, stream>>>(modulator, pm_w, qpart);
    k_w2<<<5120, 256, 0, stream>>>(po_w, pm_b, qpart, w2);
    k_gemm<<<dim3(534, 4), 512, 0, stream>>>(f0, f1, f2, f3, f4, w2, po_b, out);
}

// Round 2
// 223.156 us; speedup vs baseline: 1.5695x; 1.5695x over previous
//
#include <hip/hip_runtime.h>
#include <hip/hip_bf16.h>

// ---------------------------------------------------------------------------
// RPN_Modulator fused pipeline (3 kernels):
//   k_q   : qpart[s,k,bi,c] = partial_c' modulator[bi,c'] * pm_w[k,c,c']   (4-way K-split)
//   k_w2  : w2[k,bi,o,c] = bf16(po_w[k,o,c] * (sum_s qpart + pm_b[k,c]))   (row-major)
//   k_gemm: out[k,bi,o,n] = sum_c w2[o,c]*bf16(feats[k][b,c,n]) + po_b[k,o]
//
// Round-1: REVERT the round-0 operand swap (it was 2x slower: doubled inner
// global loads + 2x wn-duplicated w2 L2 reads + write amplification 712 vs
// 559MB). Back to A=w2 (global, 2 loads/kk), B=feats (LDS), scalar stores
// that fully cover 128B lines per wave. One change on top of the known-good
// structure: n-tile 64 -> 128 (ni 4 -> 8, LDS 64KB, 268 tiles). Halves w2
// L2 traffic and doubles MFMA:global-load ratio (16 MFMA per 2 loads per kk)
// -> better latency tolerance at the same 16 waves/CU. k_q keeps the 4-output
// version (halved modulator L2 re-reads).
// ---------------------------------------------------------------------------

typedef __bf16 bf16x8 __attribute__((ext_vector_type(8)));
typedef float  f32x4  __attribute__((ext_vector_type(4)));
typedef unsigned short u16;

__device__ __forceinline__ unsigned pack2(float lo, float hi) {
    __hip_bfloat162 h = __float22bfloat162_rn(make_float2(lo, hi));
    union { __hip_bfloat162 h; unsigned u; } cv; cv.h = h; return cv.u;
}

// tiles-of-128 per level: {200,50,13,4,1}, total 268
__device__ __forceinline__ void decode_tile(int x, int& k, int& nt, int& N, size_t& oo) {
    if (x < 200)      { k = 0; nt = x;       N = 25600; oo = 0; }
    else if (x < 250) { k = 1; nt = x - 200; N = 6400;  oo = 104857600; }
    else if (x < 263) { k = 2; nt = x - 250; N = 1600;  oo = 131072000; }
    else if (x < 267) { k = 3; nt = x - 263; N = 400;   oo = 137625600; }
    else              { k = 4; nt = x - 267; N = 100;   oo = 139264000; }
}

// ---------------- Kernel 1: q partials, 4-way split over K ----------------
// 4 outputs per block: halves modulator L2 traffic vs 2-output version.
__global__ __launch_bounds__(256) void k_q(
    const float* __restrict__ modulator,  // [16][12544]
    const float* __restrict__ pm_w,       // [5][256][12544]
    float* __restrict__ qpart)            // [4][5][16][256]
{
    int o4 = blockIdx.x;                  // outputs o4 + {0,64,128,192}
    int k  = blockIdx.y;
    int s  = blockIdx.z;                  // K-split 0..3, 784 float4 each
    int t  = threadIdx.x;
    float acc[4][16];
#pragma unroll
    for (int j = 0; j < 4; ++j)
#pragma unroll
        for (int bi = 0; bi < 16; ++bi) acc[j][bi] = 0.f;
    const float4* mod4 = (const float4*)modulator;
    const float4* wp0 = (const float4*)(pm_w + ((size_t)k * 256 + o4      ) * 12544);
    const float4* wp1 = (const float4*)(pm_w + ((size_t)k * 256 + o4 +  64) * 12544);
    const float4* wp2 = (const float4*)(pm_w + ((size_t)k * 256 + o4 + 128) * 12544);
    const float4* wp3 = (const float4*)(pm_w + ((size_t)k * 256 + o4 + 192) * 12544);
    for (int it = 0; it < 4; ++it) {
        int jj = it * 256 + t;
        if (jj < 784) {
            int jx = s * 784 + jj;
            float4 wv0 = wp0[jx], wv1 = wp1[jx], wv2 = wp2[jx], wv3 = wp3[jx];
#pragma unroll
            for (int bi = 0; bi < 16; ++bi) {
                float4 m = mod4[bi * 3136 + jx];
                acc[0][bi] += wv0.x * m.x + wv0.y * m.y + wv0.z * m.z + wv0.w * m.w;
                acc[1][bi] += wv1.x * m.x + wv1.y * m.y + wv1.z * m.z + wv1.w * m.w;
                acc[2][bi] += wv2.x * m.x + wv2.y * m.y + wv2.z * m.z + wv2.w * m.w;
                acc[3][bi] += wv3.x * m.x + wv3.y * m.y + wv3.z * m.z + wv3.w * m.w;
            }
        }
    }
#pragma unroll
    for (int j = 0; j < 4; ++j)
#pragma unroll
        for (int bi = 0; bi < 16; ++bi)
#pragma unroll
            for (int off = 32; off > 0; off >>= 1)
                acc[j][bi] += __shfl_down(acc[j][bi], off);
    __shared__ float red[4][64];
    int w = t >> 6, lane = t & 63;
    if (lane == 0) {
#pragma unroll
        for (int j = 0; j < 4; ++j)
#pragma unroll
            for (int bi = 0; bi < 16; ++bi) red[w][j * 16 + bi] = acc[j][bi];
    }
    __syncthreads();
    if (t < 64) {
        float v = red[0][t] + red[1][t] + red[2][t] + red[3][t];
        int bi = t & 15;
        int o  = o4 + (t >> 4) * 64;
        qpart[(((size_t)s * 5 + k) * 16 + bi) * 256 + o] = v;
    }
}

// ---------------- Kernel 2: W2 = bf16(po_w * (sum qpart + pm_b)), 4c/thread
__global__ __launch_bounds__(256) void k_w2(
    const float* __restrict__ po_w,       // [5][256][256]
    const float* __restrict__ pm_b,       // [5][256]
    const float* __restrict__ qpart,      // [4][5][16][256]
    u16* __restrict__ w2)                 // [5][16][256][256] bf16
{
    int idx4 = blockIdx.x * 256 + threadIdx.x;   // 5*2^18 threads, 4 c each
    int c4 = idx4 & 63;
    int o  = (idx4 >> 6) & 255;
    int bi = (idx4 >> 14) & 15;
    int k  = idx4 >> 18;
    size_t qi = ((size_t)(k * 16 + bi)) * 256 + c4 * 4;
    f32x4 q0 = *(const f32x4*)(qpart + qi);
    f32x4 q1 = *(const f32x4*)(qpart + qi + 20480);
    f32x4 q2 = *(const f32x4*)(qpart + qi + 40960);
    f32x4 q3 = *(const f32x4*)(qpart + qi + 61440);
    f32x4 pb = *(const f32x4*)(pm_b + k * 256 + c4 * 4);
    f32x4 q  = q0 + q1 + q2 + q3 + pb;
    f32x4 w  = *(const f32x4*)(po_w + ((size_t)(k * 256 + o)) * 256 + c4 * 4);
    uint2 r;
    r.x = pack2(w[0] * q[0], w[1] * q[1]);
    r.y = pack2(w[2] * q[2], w[3] * q[3]);
    *(uint2*)(w2 + (size_t)idx4 * 4) = r;
}

// ---------------- Kernel 3: fused transpose + GEMM over all levels ---------
// block: 512 threads = 8 waves; 128 out-cols x full M=256 x 4 instances;
// each wave owns 32 rows (acc 2x8). LDS: feats [128n][256c] bf16, swizzled.
// A-fragments direct from L2-resident w2 (64B/row bursts); fp32->bf16
// transpose fused into XOR-swizzled LDS; single sync; scalar nontemporal
// stores (coalesced: per wave each out row gets 64 consecutive floats).
__global__ __launch_bounds__(512, 4) void k_gemm(
    const float* __restrict__ f0, const float* __restrict__ f1,
    const float* __restrict__ f2, const float* __restrict__ f3,
    const float* __restrict__ f4,
    const u16* __restrict__ w2,      // [k][bi][o][c] bf16 row-major
    const float* __restrict__ po_b,  // [5][256]
    float* __restrict__ out)         // [k][bi][o][n] fp32
{
    __shared__ __align__(16) u16 ldsB[128 * 256];   // 64 KB
    int k, nt, N; size_t oo;
    decode_tile(blockIdx.x, k, nt, N, oo);
    const float* fsrc = (k == 0) ? f0 : (k == 1) ? f1 : (k == 2) ? f2 : (k == 3) ? f3 : f4;
    const int b = blockIdx.y;
    const int t = threadIdx.x;
    const int n0 = nt * 128;

    // ---- stage: fp32 [c][n] -> bf16 LDS [n][c], swizzled; single sync ----
    {
        const float* s = fsrc + (size_t)b * 256 * N + n0;
        int ng = t & 31, grp = t >> 5;          // ng: float4 along n; grp 0..15: c-pair group
        bool inb = (n0 + ng * 4) < N;           // N%4==0 -> whole float4 in/out
#pragma unroll
        for (int j = 0; j < 8; ++j) {
            int p = j * 16 + grp;               // c-pair 0..127 (c=2p,2p+1)
            f32x4 v0 = {0.f, 0.f, 0.f, 0.f}, v1 = {0.f, 0.f, 0.f, 0.f};
            if (inb) {
                v0 = *(const f32x4*)(s + (size_t)(2 * p) * N + ng * 4);
                v1 = *(const f32x4*)(s + (size_t)(2 * p + 1) * N + ng * 4);
            }
#pragma unroll
            for (int e = 0; e < 4; ++e) {
                int n = ng * 4 + e;
                unsigned off = (unsigned)(n << 9) + (unsigned)(p << 2);
                off ^= (unsigned)((n & 7) << 4);
                *(unsigned*)((char*)ldsB + off) = pack2(v0[e], v1[e]);
            }
        }
    }
    __syncthreads();

    const int lane = t & 63, w = t >> 6;        // w 0..7, 32 rows each
    const int lr = lane & 15, lg = lane >> 4;
    const float* pb = po_b + k * 256;
    float* obase0 = out + oo;

#pragma unroll 1
    for (int i = 0; i < 4; ++i) {
        const u16* wsrc = w2 + ((size_t)(k * 16 + b * 4 + i) << 16);
        float* obase = obase0 + (size_t)(b * 4 + i) * 256 * N;
        f32x4 acc[2][8];
#pragma unroll
        for (int mi = 0; mi < 2; ++mi)
#pragma unroll
            for (int ni = 0; ni < 8; ++ni)
                acc[mi][ni] = (f32x4){0.f, 0.f, 0.f, 0.f};

#pragma unroll 2
        for (int kk = 0; kk < 8; ++kk) {        // K = 256 = 8 x 32
            bf16x8 a[2], bb[8];
#pragma unroll
            for (int mi = 0; mi < 2; ++mi)
                a[mi] = *(const bf16x8*)(wsrc + (size_t)(w * 32 + mi * 16 + lr) * 256 + kk * 32 + lg * 8);
#pragma unroll
            for (int ni = 0; ni < 8; ++ni) {
                int row = ni * 16 + lr;
                unsigned off = (unsigned)(row << 9) + (unsigned)(kk << 6) + (unsigned)(lg << 4);
                off ^= (unsigned)((row & 7) << 4);
                bb[ni] = *(const bf16x8*)((const char*)ldsB + off);
            }
#pragma unroll
            for (int mi = 0; mi < 2; ++mi)
#pragma unroll
                for (int ni = 0; ni < 8; ++ni)
                    acc[mi][ni] = __builtin_amdgcn_mfma_f32_16x16x32_bf16(a[mi], bb[ni], acc[mi][ni], 0, 0, 0);
        }

        // epilogue: D col = lane&15 (n), row = (lane>>4)*4 + rr (o); streaming stores
#pragma unroll
        for (int mi = 0; mi < 2; ++mi) {
#pragma unroll
            for (int rr = 0; rr < 4; ++rr) {
                int orow = w * 32 + mi * 16 + lg * 4 + rr;
                float bias = pb[orow];
#pragma unroll
                for (int ni = 0; ni < 8; ++ni) {
                    int ocol = n0 + ni * 16 + lr;
                    if (ocol < N)
                        __builtin_nontemporal_store(acc[mi][ni][rr] + bias,
                                                    obase + (size_t)orow * N + ocol);
                }
            }
        }
    }
}

// ---------------------------------------------------------------------------
extern "C" void kernel_launch(void* const* d_in, const int* in_sizes, int n_in,
                              void* d_out, int out_size, void* d_ws, size_t ws_size,
                              hipStream_t stream) {
    const float* f0 = (const float*)d_in[0];
    const float* f1 = (const float*)d_in[1];
    const float* f2 = (const float*)d_in[2];
    const float* f3 = (const float*)d_in[3];
    const float* f4 = (const float*)d_in[4];
    const float* modulator = (const float*)d_in[5];
    const float* pm_w = (const float*)d_in[6];
    const float* pm_b = (const float*)d_in[7];
    const float* po_w = (const float*)d_in[8];
    const float* po_b = (const float*)d_in[9];
    float* out = (float*)d_out;

    // workspace: w2 bf16 (5,242,880 u16) | qpart (81,920 f32)  ~= 10.8 MB
    u16* w2 = (u16*)d_ws;
    float* qpart = (float*)(w2 + (size_t)5 * 16 * 256 * 256);

    k_q<<<dim3(64, 5, 4), 256, 0, stream>>>(modulator, pm_w, qpart);
    k_w2<<<5120, 256, 0, stream>>>(po_w, pm_b, qpart, w2);
    k_gemm<<<dim3(268, 4), 512, 0, stream>>>(f0, f1, f2, f3, f4, w2, po_b, out);
}

// Round 3
// 193.091 us; speedup vs baseline: 1.8138x; 1.1557x over previous
//
#include <hip/hip_runtime.h>
#include <hip/hip_bf16.h>

// ---------------------------------------------------------------------------
// RPN_Modulator fused pipeline (3 kernels):
//   k_q   : qpart[s,k,bi,c] = partial_c' modulator[bi,c'] * pm_w[k,c,c']   (4-way K-split)
//   k_w2  : w2[k,bi,o,c] = bf16(po_w[k,o,c] * (sum_s qpart + pm_b[k,c]))   (row-major)
//   k_gemm: out[k,bi,o,n] = sum_c w2[o,c]*bf16(feats[k][b,c,n]) + po_b[k,o]
//
// Round-2 changes vs 223us (128-tile, 16x16x32):
//  * k_gemm MFMA shape -> 32x32x16. D-layout (col=lane&31, row=(reg&3)+
//    8*(reg>>2)+4*(lane>>5)) makes every scalar NT store instruction cover
//    two FULL 128B lines (32 consecutive n per row-group) -> no partial-line
//    write amplification. Bias folded into acc init. Same tile (128n x 256o
//    x 4 inst), same LDS 64KB, same load counts per K.
//  * staging swizzle h(n) = (n&7)^((n>>2)&7) + b64 writes (4x4 register
//    transpose per thread): write-side bank conflicts 16-way -> conflict-free
//    (h is exactly 4-per-value over stride-4 write sets AND consecutive-32
//    read sets); reads stay at the b128 wave64 minimum.
// ---------------------------------------------------------------------------

typedef __bf16 bf16x8 __attribute__((ext_vector_type(8)));
typedef float  f32x4  __attribute__((ext_vector_type(4)));
typedef float  f32x16 __attribute__((ext_vector_type(16)));
typedef unsigned short u16;

__device__ __forceinline__ unsigned pack2(float lo, float hi) {
    __hip_bfloat162 h = __float22bfloat162_rn(make_float2(lo, hi));
    union { __hip_bfloat162 h; unsigned u; } cv; cv.h = h; return cv.u;
}

// tiles-of-128 per level: {200,50,13,4,1}, total 268
__device__ __forceinline__ void decode_tile(int x, int& k, int& nt, int& N, size_t& oo) {
    if (x < 200)      { k = 0; nt = x;       N = 25600; oo = 0; }
    else if (x < 250) { k = 1; nt = x - 200; N = 6400;  oo = 104857600; }
    else if (x < 263) { k = 2; nt = x - 250; N = 1600;  oo = 131072000; }
    else if (x < 267) { k = 3; nt = x - 263; N = 400;   oo = 137625600; }
    else              { k = 4; nt = x - 267; N = 100;   oo = 139264000; }
}

// ---------------- Kernel 1: q partials, 4-way split over K ----------------
__global__ __launch_bounds__(256) void k_q(
    const float* __restrict__ modulator,  // [16][12544]
    const float* __restrict__ pm_w,       // [5][256][12544]
    float* __restrict__ qpart)            // [4][5][16][256]
{
    int o4 = blockIdx.x;                  // outputs o4 + {0,64,128,192}
    int k  = blockIdx.y;
    int s  = blockIdx.z;                  // K-split 0..3, 784 float4 each
    int t  = threadIdx.x;
    float acc[4][16];
#pragma unroll
    for (int j = 0; j < 4; ++j)
#pragma unroll
        for (int bi = 0; bi < 16; ++bi) acc[j][bi] = 0.f;
    const float4* mod4 = (const float4*)modulator;
    const float4* wp0 = (const float4*)(pm_w + ((size_t)k * 256 + o4      ) * 12544);
    const float4* wp1 = (const float4*)(pm_w + ((size_t)k * 256 + o4 +  64) * 12544);
    const float4* wp2 = (const float4*)(pm_w + ((size_t)k * 256 + o4 + 128) * 12544);
    const float4* wp3 = (const float4*)(pm_w + ((size_t)k * 256 + o4 + 192) * 12544);
    for (int it = 0; it < 4; ++it) {
        int jj = it * 256 + t;
        if (jj < 784) {
            int jx = s * 784 + jj;
            float4 wv0 = wp0[jx], wv1 = wp1[jx], wv2 = wp2[jx], wv3 = wp3[jx];
#pragma unroll
            for (int bi = 0; bi < 16; ++bi) {
                float4 m = mod4[bi * 3136 + jx];
                acc[0][bi] += wv0.x * m.x + wv0.y * m.y + wv0.z * m.z + wv0.w * m.w;
                acc[1][bi] += wv1.x * m.x + wv1.y * m.y + wv1.z * m.z + wv1.w * m.w;
                acc[2][bi] += wv2.x * m.x + wv2.y * m.y + wv2.z * m.z + wv2.w * m.w;
                acc[3][bi] += wv3.x * m.x + wv3.y * m.y + wv3.z * m.z + wv3.w * m.w;
            }
        }
    }
#pragma unroll
    for (int j = 0; j < 4; ++j)
#pragma unroll
        for (int bi = 0; bi < 16; ++bi)
#pragma unroll
            for (int off = 32; off > 0; off >>= 1)
                acc[j][bi] += __shfl_down(acc[j][bi], off);
    __shared__ float red[4][64];
    int w = t >> 6, lane = t & 63;
    if (lane == 0) {
#pragma unroll
        for (int j = 0; j < 4; ++j)
#pragma unroll
            for (int bi = 0; bi < 16; ++bi) red[w][j * 16 + bi] = acc[j][bi];
    }
    __syncthreads();
    if (t < 64) {
        float v = red[0][t] + red[1][t] + red[2][t] + red[3][t];
        int bi = t & 15;
        int o  = o4 + (t >> 4) * 64;
        qpart[(((size_t)s * 5 + k) * 16 + bi) * 256 + o] = v;
    }
}

// ---------------- Kernel 2: W2 = bf16(po_w * (sum qpart + pm_b)), 4c/thread
__global__ __launch_bounds__(256) void k_w2(
    const float* __restrict__ po_w,       // [5][256][256]
    const float* __restrict__ pm_b,       // [5][256]
    const float* __restrict__ qpart,      // [4][5][16][256]
    u16* __restrict__ w2)                 // [5][16][256][256] bf16
{
    int idx4 = blockIdx.x * 256 + threadIdx.x;   // 5*2^18 threads, 4 c each
    int c4 = idx4 & 63;
    int o  = (idx4 >> 6) & 255;
    int bi = (idx4 >> 14) & 15;
    int k  = idx4 >> 18;
    size_t qi = ((size_t)(k * 16 + bi)) * 256 + c4 * 4;
    f32x4 q0 = *(const f32x4*)(qpart + qi);
    f32x4 q1 = *(const f32x4*)(qpart + qi + 20480);
    f32x4 q2 = *(const f32x4*)(qpart + qi + 40960);
    f32x4 q3 = *(const f32x4*)(qpart + qi + 61440);
    f32x4 pb = *(const f32x4*)(pm_b + k * 256 + c4 * 4);
    f32x4 q  = q0 + q1 + q2 + q3 + pb;
    f32x4 w  = *(const f32x4*)(po_w + ((size_t)(k * 256 + o)) * 256 + c4 * 4);
    uint2 r;
    r.x = pack2(w[0] * q[0], w[1] * q[1]);
    r.y = pack2(w[2] * q[2], w[3] * q[3]);
    *(uint2*)(w2 + (size_t)idx4 * 4) = r;
}

// ---------------- Kernel 3: fused transpose + GEMM over all levels ---------
// block: 512 threads = 8 waves; 128 out-cols x full M=256 x 4 instances;
// each wave owns 32 o-rows via ONE 32-row m-tile, 4 n-tiles of 32 (32x32x16
// MFMA, acc 4 x f32x16). LDS: feats [128n][256c] bf16, h-swizzled. A direct
// from L2-resident w2. Every store instr = two full 128B lines.
__global__ __launch_bounds__(512, 4) void k_gemm(
    const float* __restrict__ f0, const float* __restrict__ f1,
    const float* __restrict__ f2, const float* __restrict__ f3,
    const float* __restrict__ f4,
    const u16* __restrict__ w2,      // [k][bi][o][c] bf16 row-major
    const float* __restrict__ po_b,  // [5][256]
    float* __restrict__ out)         // [k][bi][o][n] fp32
{
    __shared__ __align__(16) u16 ldsB[128 * 256];   // 64 KB
    int k, nt, N; size_t oo;
    decode_tile(blockIdx.x, k, nt, N, oo);
    const float* fsrc = (k == 0) ? f0 : (k == 1) ? f1 : (k == 2) ? f2 : (k == 3) ? f3 : f4;
    const int b = blockIdx.y;
    const int t = threadIdx.x;
    const int n0 = nt * 128;

    // ---- stage: fp32 [c][n] -> bf16 LDS [n][c], h-swizzled b64 writes ----
    // thread: 4x4 register transpose; writes c-quad (8B) per n.
    {
        const int ng = t & 31, grp = t >> 5;    // ng: float4 along n; grp 0..15
        const bool inb = (n0 + ng * 4) < N;     // N%4==0 -> whole float4 in/out
        const float* s = fsrc + (size_t)b * 256 * N + n0 + ng * 4;
#pragma unroll
        for (int j = 0; j < 4; ++j) {
            int q = j * 16 + grp;               // c-quad: c = 4q..4q+3
            f32x4 v0 = {0.f,0.f,0.f,0.f}, v1 = {0.f,0.f,0.f,0.f};
            f32x4 v2 = {0.f,0.f,0.f,0.f}, v3 = {0.f,0.f,0.f,0.f};
            if (inb) {
                v0 = *(const f32x4*)(s + (size_t)(4 * q + 0) * N);
                v1 = *(const f32x4*)(s + (size_t)(4 * q + 1) * N);
                v2 = *(const f32x4*)(s + (size_t)(4 * q + 2) * N);
                v3 = *(const f32x4*)(s + (size_t)(4 * q + 3) * N);
            }
#pragma unroll
            for (int e = 0; e < 4; ++e) {
                int n = ng * 4 + e;
                unsigned h = ((unsigned)n & 7u) ^ (((unsigned)n >> 2) & 7u);
                unsigned off = ((unsigned)n << 9) + ((unsigned)q << 3);
                off ^= (h << 4);
                uint2 wv; wv.x = pack2(v0[e], v1[e]); wv.y = pack2(v2[e], v3[e]);
                *(uint2*)((char*)ldsB + off) = wv;
            }
        }
    }
    __syncthreads();

    const int lane = t & 63, w = t >> 6;        // 8 waves, 32 o-rows each
    const int l31 = lane & 31, lg5 = lane >> 5;
    const float* pb = po_b + k * 256;
    float* obase0 = out + oo;

    // bias: rows for acc reg q are w*32 + (q&3) + 8*(q>>2) + 4*lg5
    f32x4 bias4[4];
#pragma unroll
    for (int m = 0; m < 4; ++m)
        bias4[m] = *(const f32x4*)(pb + w * 32 + 8 * m + 4 * lg5);

    // B (feats) LDS addressing: row = ni*32 + l31; granule = (kk<<1)|lg5,
    // stored at granule ^ h(row). mrow = rowbase, mx = (lg5 ^ h)<<4;
    // addr = mrow + ((kk<<5) ^ mx)  (XOR safe: disjoint-carry by construction)
    unsigned mrow[4], mx[4];
#pragma unroll
    for (int ni = 0; ni < 4; ++ni) {
        int row = ni * 32 + l31;
        unsigned h = ((unsigned)row & 7u) ^ (((unsigned)row >> 2) & 7u);
        mrow[ni] = (unsigned)row << 9;
        mx[ni] = ((unsigned)lg5 ^ h) << 4;
    }

#pragma unroll 1
    for (int i = 0; i < 4; ++i) {
        // A (w2): row = w*32 + l31, k-bytes = kk*32 + lg5*16
        const u16* wsrc = w2 + ((size_t)(k * 16 + b * 4 + i) << 16)
                        + (size_t)(w * 32 + l31) * 256 + lg5 * 8;
        float* obase = obase0 + (size_t)(b * 4 + i) * 256 * N;

        f32x16 acc[4];
#pragma unroll
        for (int ni = 0; ni < 4; ++ni)
#pragma unroll
            for (int q = 0; q < 16; ++q)
                acc[ni][q] = bias4[q >> 2][q & 3];

#pragma unroll 2
        for (int kk = 0; kk < 16; ++kk) {       // K = 256 = 16 x 16
            bf16x8 a = *(const bf16x8*)(wsrc + kk * 16);
            bf16x8 bb[4];
            unsigned kb = (unsigned)kk << 5;
#pragma unroll
            for (int ni = 0; ni < 4; ++ni)
                bb[ni] = *(const bf16x8*)((const char*)ldsB + (mrow[ni] + (kb ^ mx[ni])));
#pragma unroll
            for (int ni = 0; ni < 4; ++ni)
                acc[ni] = __builtin_amdgcn_mfma_f32_32x32x16_bf16(a, bb[ni], acc[ni], 0, 0, 0);
        }

        // epilogue: D col = l31 (n), row = (q&3)+8*(q>>2)+4*lg5 (o).
        // Each store instr: 2 row-groups x 32 consecutive n = 2 full lines.
#pragma unroll
        for (int ni = 0; ni < 4; ++ni) {
            int ocol = n0 + ni * 32 + l31;
            if (ocol < N) {
                float* op = obase + ocol;
#pragma unroll
                for (int q = 0; q < 16; ++q) {
                    int orow = w * 32 + (q & 3) + 8 * (q >> 2) + 4 * lg5;
                    __builtin_nontemporal_store(acc[ni][q], op + (size_t)orow * N);
                }
            }
        }
    }
}

// ---------------------------------------------------------------------------
extern "C" void kernel_launch(void* const* d_in, const int* in_sizes, int n_in,
                              void* d_out, int out_size, void* d_ws, size_t ws_size,
                              hipStream_t stream) {
    const float* f0 = (const float*)d_in[0];
    const float* f1 = (const float*)d_in[1];
    const float* f2 = (const float*)d_in[2];
    const float* f3 = (const float*)d_in[3];
    const float* f4 = (const float*)d_in[4];
    const float* modulator = (const float*)d_in[5];
    const float* pm_w = (const float*)d_in[6];
    const float* pm_b = (const float*)d_in[7];
    const float* po_w = (const float*)d_in[8];
    const float* po_b = (const float*)d_in[9];
    float* out = (float*)d_out;

    // workspace: w2 bf16 (5,242,880 u16) | qpart (81,920 f32)  ~= 10.8 MB
    u16* w2 = (u16*)d_ws;
    float* qpart = (float*)(w2 + (size_t)5 * 16 * 256 * 256);

    k_q<<<dim3(64, 5, 4), 256, 0, stream>>>(modulator, pm_w, qpart);
    k_w2<<<5120, 256, 0, stream>>>(po_w, pm_b, qpart, w2);
    k_gemm<<<dim3(268, 4), 512, 0, stream>>>(f0, f1, f2, f3, f4, w2, po_b, out);
}